// Round 8
// baseline (619.056 us; speedup 1.0000x reference)
//
#include <hip/hip_runtime.h>
#include <hip/hip_bf16.h>
#include <cstdint>
#include <cstddef>

typedef __bf16 bf16;
typedef bf16 bf16x4 __attribute__((ext_vector_type(4)));
typedef bf16 bf16x8 __attribute__((ext_vector_type(8)));
typedef float f32x4 __attribute__((ext_vector_type(4)));

#define HEAD_DIM 256
#define NHEADS 8
#define NKV 4
#define BATCH 2
#define SEQ 2048
#define IND 5120
#define HID 2560
#define ROWS (BATCH*SEQ)   // 4096
#define NQKV 4096          // 2048 + 1024 + 1024
#define CHUNKS_PER_BH 80   // 64-q tiles: sum over qt=0..31 of ceil((qt+1)/8)

__device__ __forceinline__ f32x4 mfma16(bf16x8 a, bf16x8 b, f32x4 c) {
  return __builtin_amdgcn_mfma_f32_16x16x32_bf16(a, b, c, 0, 0, 0);
}

// ---------------- fused cast fp32 -> bf16 for all 5 tensors ----------------
__global__ void cast_all(const float* __restrict__ hs, const float* __restrict__ wq,
                         const float* __restrict__ wk, const float* __restrict__ wv,
                         const float* __restrict__ wo,
                         bf16* __restrict__ dst01, bf16* __restrict__ dwo) {
  long i = ((long)blockIdx.x * 256 + threadIdx.x) * 8;
  const float* src; bf16* dst;
  if (i < 20971520L)      { src = hs + i;              dst = dst01 + i; }
  else if (i < 31457280L) { src = wq + (i - 20971520); dst = dst01 + i; }
  else if (i < 36700160L) { src = wk + (i - 31457280); dst = dst01 + i; }
  else if (i < 41943040L) { src = wv + (i - 36700160); dst = dst01 + i; }
  else                    { src = wo + (i - 41943040); dst = dwo + (i - 41943040); }
  float4 a = *(const float4*)(src);
  float4 b = *(const float4*)(src + 4);
  bf16x8 o;
  o[0] = (bf16)a.x; o[1] = (bf16)a.y; o[2] = (bf16)a.z; o[3] = (bf16)a.w;
  o[4] = (bf16)b.x; o[5] = (bf16)b.y; o[6] = (bf16)b.z; o[7] = (bf16)b.w;
  *(bf16x8*)dst = o;
}

// ---------------- pipelined BT GEMM 256x256 (GEMM1) ----------------
// BK=32, 512 thr / 8 waves (2Mx4N), 4-slot LDS ring (128 KiB), 3 tiles
// prefetched, counted vmcnt, reads-one-iter-ahead, conflict-free swizzle
// slot = chunk ^ ((row>>1)&3).
template<typename OutT>
__global__ __launch_bounds__(512, 2) void gemm_pipe(const bf16* __restrict__ A,
                                                    const bf16* __restrict__ B,
                                                    OutT* __restrict__ C,
                                                    int M, int N, int K) {
  extern __shared__ bf16 smem[];
  const int tid = threadIdx.x;
  const int lane = tid & 63, w = tid >> 6;
  const int wm = w >> 2, wn = w & 3;
  const int l15 = lane & 15, lg = lane >> 4;
  const int gx = gridDim.x;
  const int nwg = gx * gridDim.y;
  const int id = blockIdx.y * gx + blockIdx.x;
  const int nid = (id & 7) * (nwg >> 3) + (id >> 3);   // bijective: nwg % 8 == 0
  const int m0 = (nid / gx) * 256, n0 = (nid % gx) * 256;
  const int NT = K >> 5;   // even, >= 4

  auto stage = [&](int slot, int kt) {
    bf16* sl = smem + slot * 16384;
    #pragma unroll
    for (int i = 0; i < 2; ++i) {
      int cid = i * 512 + tid;
      int sch = (cid & 3) ^ ((cid >> 3) & 3);
      __builtin_amdgcn_global_load_lds(
        (const __attribute__((address_space(1))) void*)(A + (size_t)(m0 + (cid >> 2)) * K + kt * 32 + sch * 8),
        (__attribute__((address_space(3))) void*)(sl + cid * 8), 16, 0, 0);
    }
    #pragma unroll
    for (int i = 0; i < 2; ++i) {
      int cid = i * 512 + tid;
      int sch = (cid & 3) ^ ((cid >> 3) & 3);
      __builtin_amdgcn_global_load_lds(
        (const __attribute__((address_space(1))) void*)(B + (size_t)(n0 + (cid >> 2)) * K + kt * 32 + sch * 8),
        (__attribute__((address_space(3))) void*)(sl + 8192 + cid * 8), 16, 0, 0);
    }
  };

  const int ach = lg ^ ((l15 >> 1) & 3);
  const int aoff = ((wm * 128 + l15) * 4 + ach) * 8;
  const int boff = 8192 + ((wn * 64 + l15) * 4 + ach) * 8;

  auto read_slot = [&](const bf16* sl, bf16x8 (&a)[8], bf16x8 (&b)[4]) {
    #pragma unroll
    for (int mi = 0; mi < 8; ++mi) a[mi] = *(const bf16x8*)&sl[aoff + mi * 512];
    #pragma unroll
    for (int ni = 0; ni < 4; ++ni) b[ni] = *(const bf16x8*)&sl[boff + ni * 512];
  };

  f32x4 acc[8][4] = {};
  auto domfma = [&](bf16x8 (&a)[8], bf16x8 (&b)[4]) {
    __builtin_amdgcn_s_setprio(1);
    #pragma unroll
    for (int ni = 0; ni < 4; ++ni)
      #pragma unroll
      for (int mi = 0; mi < 8; ++mi)
        acc[mi][ni] = mfma16(a[mi], b[ni], acc[mi][ni]);
    __builtin_amdgcn_s_setprio(0);
  };

  bf16x8 aE[8], bE[4], aO[8], bO[4];
  stage(0, 0); stage(1, 1); stage(2, 2);
  asm volatile("s_waitcnt vmcnt(8)" ::: "memory");
  __builtin_amdgcn_s_barrier();
  __builtin_amdgcn_sched_barrier(0);
  read_slot(smem, aE, bE);

  int t = 0;
  for (; t < NT - 2; t += 2) {
    asm volatile("s_waitcnt vmcnt(4)" ::: "memory");
    __builtin_amdgcn_s_barrier();
    __builtin_amdgcn_sched_barrier(0);
    read_slot(smem + ((t + 1) & 3) * 16384, aO, bO);
    { int kt = t + 3; if (kt > NT - 1) kt = NT - 1; stage((t + 3) & 3, kt); }
    domfma(aE, bE);
    asm volatile("s_waitcnt vmcnt(4)" ::: "memory");
    __builtin_amdgcn_s_barrier();
    __builtin_amdgcn_sched_barrier(0);
    read_slot(smem + ((t + 2) & 3) * 16384, aE, bE);
    { int kt = t + 4; if (kt > NT - 1) kt = NT - 1; stage((t + 4) & 3, kt); }
    domfma(aO, bO);
  }
  asm volatile("s_waitcnt vmcnt(4)" ::: "memory");
  __builtin_amdgcn_s_barrier();
  __builtin_amdgcn_sched_barrier(0);
  read_slot(smem + ((NT - 1) & 3) * 16384, aO, bO);
  domfma(aE, bE);
  domfma(aO, bO);

  #pragma unroll
  for (int mi = 0; mi < 8; ++mi)
    #pragma unroll
    for (int ni = 0; ni < 4; ++ni) {
      int row = m0 + wm * 128 + mi * 16 + lg * 4;
      int col = n0 + wn * 64 + ni * 16 + l15;
      #pragma unroll
      for (int r = 0; r < 4; ++r)
        C[(size_t)(row + r) * N + col] = (OutT)acc[mi][ni][r];
    }
}

// ---------------- pipelined BT GEMM 128x128 (GEMM2: better CU coverage) --------
// Same schedule, 256 thr / 4 waves (2Mx2N), per-wave 64x64 (acc[4][4]),
// 4-slot ring of 16 KiB (64 KiB total) -> 2 blocks/CU.
template<typename OutT>
__global__ __launch_bounds__(256, 2) void gemm_pipe128(const bf16* __restrict__ A,
                                                       const bf16* __restrict__ B,
                                                       OutT* __restrict__ C,
                                                       int M, int N, int K) {
  extern __shared__ bf16 smem[];  // 4 slots x (4096 A + 4096 B) bf16 = 64 KiB
  const int tid = threadIdx.x;
  const int lane = tid & 63, w = tid >> 6;
  const int wm = w >> 1, wn = w & 1;
  const int l15 = lane & 15, lg = lane >> 4;
  const int gx = gridDim.x;
  const int nwg = gx * gridDim.y;
  const int id = blockIdx.y * gx + blockIdx.x;
  const int nid = (id & 7) * (nwg >> 3) + (id >> 3);   // nwg % 8 == 0
  const int m0 = (nid / gx) * 128, n0 = (nid % gx) * 128;
  const int NT = K >> 5;

  auto stage = [&](int slot, int kt) {
    bf16* sl = smem + slot * 8192;
    #pragma unroll
    for (int i = 0; i < 2; ++i) {
      int cid = i * 256 + tid;
      int sch = (cid & 3) ^ ((cid >> 3) & 3);
      __builtin_amdgcn_global_load_lds(
        (const __attribute__((address_space(1))) void*)(A + (size_t)(m0 + (cid >> 2)) * K + kt * 32 + sch * 8),
        (__attribute__((address_space(3))) void*)(sl + cid * 8), 16, 0, 0);
    }
    #pragma unroll
    for (int i = 0; i < 2; ++i) {
      int cid = i * 256 + tid;
      int sch = (cid & 3) ^ ((cid >> 3) & 3);
      __builtin_amdgcn_global_load_lds(
        (const __attribute__((address_space(1))) void*)(B + (size_t)(n0 + (cid >> 2)) * K + kt * 32 + sch * 8),
        (__attribute__((address_space(3))) void*)(sl + 4096 + cid * 8), 16, 0, 0);
    }
  };

  const int ach = lg ^ ((l15 >> 1) & 3);
  const int aoff = ((wm * 64 + l15) * 4 + ach) * 8;
  const int boff = 4096 + ((wn * 64 + l15) * 4 + ach) * 8;

  auto read_slot = [&](const bf16* sl, bf16x8 (&a)[4], bf16x8 (&b)[4]) {
    #pragma unroll
    for (int mi = 0; mi < 4; ++mi) a[mi] = *(const bf16x8*)&sl[aoff + mi * 512];
    #pragma unroll
    for (int ni = 0; ni < 4; ++ni) b[ni] = *(const bf16x8*)&sl[boff + ni * 512];
  };

  f32x4 acc[4][4] = {};
  auto domfma = [&](bf16x8 (&a)[4], bf16x8 (&b)[4]) {
    __builtin_amdgcn_s_setprio(1);
    #pragma unroll
    for (int ni = 0; ni < 4; ++ni)
      #pragma unroll
      for (int mi = 0; mi < 4; ++mi)
        acc[mi][ni] = mfma16(a[mi], b[ni], acc[mi][ni]);
    __builtin_amdgcn_s_setprio(0);
  };

  bf16x8 aE[4], bE[4], aO[4], bO[4];
  stage(0, 0); stage(1, 1); stage(2, 2);
  asm volatile("s_waitcnt vmcnt(8)" ::: "memory");
  __builtin_amdgcn_s_barrier();
  __builtin_amdgcn_sched_barrier(0);
  read_slot(smem, aE, bE);

  int t = 0;
  for (; t < NT - 2; t += 2) {
    asm volatile("s_waitcnt vmcnt(4)" ::: "memory");
    __builtin_amdgcn_s_barrier();
    __builtin_amdgcn_sched_barrier(0);
    read_slot(smem + ((t + 1) & 3) * 8192, aO, bO);
    { int kt = t + 3; if (kt > NT - 1) kt = NT - 1; stage((t + 3) & 3, kt); }
    domfma(aE, bE);
    asm volatile("s_waitcnt vmcnt(4)" ::: "memory");
    __builtin_amdgcn_s_barrier();
    __builtin_amdgcn_sched_barrier(0);
    read_slot(smem + ((t + 2) & 3) * 8192, aE, bE);
    { int kt = t + 4; if (kt > NT - 1) kt = NT - 1; stage((t + 4) & 3, kt); }
    domfma(aO, bO);
  }
  asm volatile("s_waitcnt vmcnt(4)" ::: "memory");
  __builtin_amdgcn_s_barrier();
  __builtin_amdgcn_sched_barrier(0);
  read_slot(smem + ((NT - 1) & 3) * 8192, aO, bO);
  domfma(aE, bE);
  domfma(aO, bO);

  #pragma unroll
  for (int mi = 0; mi < 4; ++mi)
    #pragma unroll
    for (int ni = 0; ni < 4; ++ni) {
      int row = m0 + wm * 64 + mi * 16 + lg * 4;
      int col = n0 + wn * 64 + ni * 16 + l15;
      #pragma unroll
      for (int r = 0; r < 4; ++r)
        C[(size_t)(row + r) * N + col] = (OutT)acc[mi][ni][r];
    }
}

// ---------------- RoPE + reorder into Q (B,H,S,D) and K (B,KV,S,D) ----------------
__global__ void rope_reorder(const bf16* __restrict__ QKV,
                             bf16* __restrict__ Qr, bf16* __restrict__ Kr) {
  const int row = blockIdx.x;   // b*SEQ + s
  const int slot = blockIdx.y;  // 0..7 q heads, 8..11 k heads
  const int d = threadIdx.x;    // 0..127
  const int b = row >> 11, s = row & 2047;
  const bool isq = slot < 8;
  const int col0 = isq ? slot * HEAD_DIM : 2048 + (slot - 8) * HEAD_DIM;
  float x1 = (float)QKV[(size_t)row * NQKV + col0 + d];
  float x2 = (float)QKV[(size_t)row * NQKV + col0 + d + 128];
  float invf = exp2f((float)d * (-13.287712379549449f / 128.0f)); // 10000^(-d/128)
  float fr = (float)s * invf;
  float sn, cs;
  sincosf(fr, &sn, &cs);
  bf16* dst = isq ? (Qr + ((size_t)(b * NHEADS + slot) * SEQ + s) * HEAD_DIM)
                  : (Kr + ((size_t)(b * NKV + (slot - 8)) * SEQ + s) * HEAD_DIM);
  dst[d]       = (bf16)(x1 * cs - x2 * sn);
  dst[d + 128] = (bf16)(x2 * cs + x1 * sn);
}

// ---------------- V transpose: VT[bkv][d][s] ----------------
__global__ void v_transpose(const bf16* __restrict__ QKV, bf16* __restrict__ VT) {
  __shared__ bf16 tile[64][66];
  const int bkv = blockIdx.y;
  const int b = bkv >> 2, kv = bkv & 3;
  const int st = blockIdx.x & 31, dt = blockIdx.x >> 5;
  const int s0 = st * 64, d0 = dt * 64;
  const int tj = threadIdx.x & 63, ti = threadIdx.x >> 6;
  for (int i = ti; i < 64; i += 4)
    tile[i][tj] = QKV[(size_t)(b * SEQ + s0 + i) * NQKV + 3072 + kv * HEAD_DIM + d0 + tj];
  __syncthreads();
  for (int i = ti; i < 64; i += 4)
    VT[((size_t)bkv * HEAD_DIM + d0 + i) * SEQ + s0 + tj] = tile[tj][i];
}

// ---------------- flash attention v4: 4 waves, QBLK=64, K reg-prefetch, V via L2 --
// grid = 16 bh x 80 chunks = 1280 blocks, 256 thr. LDS = K 32 KB + pbuf 10 KB
// = 42 KB -> 2 blocks/CU (TLP hides LDS/L2 latency, m114). K single-buffered
// with T14 split: global->reg loads for kb+1 issued before QK(kb); after the
// post-QK barrier (all waves done reading Ks), ds_write regs->Ks; __syncthreads
// at iter end publishes Ks(kb+1). V read per-lane from L2 (drops 64 KB staging
// + halves LDS-read volume; V tile is L2-resident, ~1.1 GB total @34.5 TB/s).
__global__ __launch_bounds__(256) void flash_attn(const bf16* __restrict__ Q,
                                                  const bf16* __restrict__ Kp,
                                                  const bf16* __restrict__ VT,
                                                  bf16* __restrict__ Opart,
                                                  float* __restrict__ ML) {
  __shared__ bf16 Ks[64 * 256];       // 32 KB, 16B chunks XOR-swizzled by (row&7)
  __shared__ bf16 pbuf[4][16][80];    // 10 KB

  const int tid = threadIdx.x, lane = tid & 63, w = tid >> 6;
  const int l15 = lane & 15, lg = lane >> 4;

  const int cid = blockIdx.x;
  const int bh = cid / CHUNKS_PER_BH;
  const int c  = cid - bh * CHUNKS_PER_BH;
  int qt, ki;
  if (c < 8)       { qt = c;                 ki = 0; }
  else if (c < 24) { qt = 8  + ((c - 8) >> 1);  ki = (c - 8)  & 1; }
  else if (c < 48) { qt = 16 + (c - 24) / 3;    ki = (c - 24) % 3; }
  else             { qt = 24 + ((c - 48) >> 2); ki = (c - 48) & 3; }
  const int kb0 = ki * 8;
  const int kb1 = min(kb0 + 8, qt + 1);

  const int b = bh >> 3, h = bh & 7, kvh = h >> 1;
  const int bkv = b * NKV + kvh;
  const int q0 = qt * 64 + w * 16;

  const bf16* Qb = Q + ((size_t)bh * SEQ + q0) * HEAD_DIM;
  bf16x8 qf[8];
  #pragma unroll
  for (int dc = 0; dc < 8; ++dc)
    qf[dc] = *(const bf16x8*)&Qb[l15 * HEAD_DIM + dc * 32 + lg * 8];

  f32x4 oacc[16] = {};
  float m = -1e30f, l = 0.f;

  const bf16* Ksrc = Kp + (size_t)bkv * SEQ * HEAD_DIM;
  const bf16* Vsrc = VT + (size_t)bkv * HEAD_DIM * SEQ;

  bf16x8 vk[8];
  auto kload = [&](int kb) {
    #pragma unroll
    for (int i = 0; i < 8; ++i) {
      int id = i * 256 + tid;
      int row = id >> 5, ch = id & 31;
      vk[i] = *(const bf16x8*)&Ksrc[(size_t)(kb * 64 + row) * HEAD_DIM + ch * 8];
    }
  };
  auto kwrite = [&]() {
    #pragma unroll
    for (int i = 0; i < 8; ++i) {
      int id = i * 256 + tid;
      int row = id >> 5, ch = id & 31;
      *(bf16x8*)&Ks[(size_t)(row * 32 + (ch ^ (row & 7))) * 8] = vk[i];
    }
  };

  kload(kb0);
  kwrite();
  __syncthreads();

  for (int kb = kb0; kb < kb1; ++kb) {
    const int kbase = kb * 64;
    const bool more = (kb + 1 < kb1);
    if (more) kload(kb + 1);   // issue next K loads; land during QK/softmax

    // ---- S^T = K Q^T ----
    f32x4 sacc[4] = {};
    __builtin_amdgcn_s_setprio(1);
    #pragma unroll
    for (int j = 0; j < 4; ++j) {
      const bf16* kl = &Ks[(j * 16 + l15) * HEAD_DIM];
      #pragma unroll
      for (int dc = 0; dc < 8; ++dc) {
        int ch = (dc * 4 + lg) ^ (l15 & 7);
        bf16x8 kf = *(const bf16x8*)&kl[ch * 8];
        sacc[j] = mfma16(kf, qf[dc], sacc[j]);
      }
    }
    __builtin_amdgcn_s_setprio(0);
    asm volatile("s_barrier" ::: "memory");   // all waves done reading Ks(kb)

    // ---- mask + scale ----
    float px[4][4];
    const bool need_mask = (kbase + 63 > q0);
    #pragma unroll
    for (int j = 0; j < 4; ++j)
      #pragma unroll
      for (int r = 0; r < 4; ++r) {
        float v = sacc[j][r] * 0.0625f;   // 1/sqrt(256)
        if (need_mask) {
          int kcol = kbase + j * 16 + lg * 4 + r;
          v = (kcol <= q0 + l15) ? v : -1e30f;
        }
        px[j][r] = v;
      }

    // ---- online softmax (lane holds full 16-val row; 2 shfls) ----
    float mx = px[0][0];
    #pragma unroll
    for (int j = 0; j < 4; ++j)
      #pragma unroll
      for (int r = 0; r < 4; ++r) mx = fmaxf(mx, px[j][r]);
    mx = fmaxf(mx, __shfl_xor(mx, 16));
    mx = fmaxf(mx, __shfl_xor(mx, 32));
    float mnew = fmaxf(m, mx);
    float alpha = __expf(m - mnew);
    m = mnew;
    float s = 0.f;
    #pragma unroll
    for (int j = 0; j < 4; ++j) {
      bf16x4 pk;
      #pragma unroll
      for (int r = 0; r < 4; ++r) {
        float e = __expf(px[j][r] - mnew);
        s += e;
        pk[r] = (bf16)e;
      }
      *(bf16x4*)&pbuf[w][l15][j * 16 + lg * 4] = pk;
    }
    s += __shfl_xor(s, 16);
    s += __shfl_xor(s, 32);
    l = l * alpha + s;

    if (more) kwrite();        // Ks <- kb+1 (after barrier; compiler waits vk)

    float ar[4];
    #pragma unroll
    for (int r = 0; r < 4; ++r) ar[r] = __shfl(alpha, lg * 4 + r);
    #pragma unroll
    for (int ni = 0; ni < 16; ++ni)
      #pragma unroll
      for (int r = 0; r < 4; ++r) oacc[ni][r] *= ar[r];

    // ---- O += P V (V direct from L2, BT form) ----
    bf16x8 pa0 = *(const bf16x8*)&pbuf[w][l15][lg * 8];
    bf16x8 pa1 = *(const bf16x8*)&pbuf[w][l15][32 + lg * 8];
    __builtin_amdgcn_s_setprio(1);
    #pragma unroll
    for (int ni = 0; ni < 16; ++ni) {
      const bf16* vb = &Vsrc[(size_t)(ni * 16 + l15) * SEQ + kbase + lg * 8];
      bf16x8 v0 = *(const bf16x8*)&vb[0];
      bf16x8 v1 = *(const bf16x8*)&vb[32];
      oacc[ni] = mfma16(pa0, v0, oacc[ni]);
      oacc[ni] = mfma16(pa1, v1, oacc[ni]);
    }
    __builtin_amdgcn_s_setprio(0);
    __syncthreads();           // publish Ks(kb+1): lgkm drain + barrier
  }

  bf16* Ob = Opart + ((size_t)cid * 64 + w * 16) * HEAD_DIM;
  #pragma unroll
  for (int ni = 0; ni < 16; ++ni)
    #pragma unroll
    for (int r = 0; r < 4; ++r)
      Ob[(size_t)(lg * 4 + r) * HEAD_DIM + ni * 16 + l15] = (bf16)oacc[ni][r];
  if (lg == 0) {
    ML[((size_t)cid * 64 + w * 16 + l15) * 2]     = m;
    ML[((size_t)cid * 64 + w * 16 + l15) * 2 + 1] = l;
  }
}

// ---------------- merge partials -> ao (b, s, h*256+d) bf16 ----------------
__global__ __launch_bounds__(256) void flash_merge(const bf16* __restrict__ Opart,
                                                   const float* __restrict__ ML,
                                                   bf16* __restrict__ AO) {
  const int bh = blockIdx.x, qt = blockIdx.y;   // 16 x 32
  const int b = bh >> 3, h = bh & 7;
  int cbase, nc;
  if (qt < 8)       { cbase = qt;                nc = 1; }
  else if (qt < 16) { cbase = 8  + 2 * (qt - 8);  nc = 2; }
  else if (qt < 24) { cbase = 24 + 3 * (qt - 16); nc = 3; }
  else              { cbase = 48 + 4 * (qt - 24); nc = 4; }
  const int cid0 = bh * CHUNKS_PER_BH + cbase;

  const int tid = threadIdx.x;
  const int row = tid >> 2, dseg = (tid & 3) * 64;

  float mi[4], li[4];
  float M = -1e30f;
  for (int i = 0; i < nc; ++i) {
    mi[i] = ML[((size_t)(cid0 + i) * 64 + row) * 2];
    li[i] = ML[((size_t)(cid0 + i) * 64 + row) * 2 + 1];
    M = fmaxf(M, mi[i]);
  }
  float wgt[4], L = 0.f;
  for (int i = 0; i < nc; ++i) {
    wgt[i] = __expf(mi[i] - M);
    L += li[i] * wgt[i];
  }
  const float inv = 1.0f / L;

  bf16* dst = AO + ((size_t)(b * SEQ + qt * 64 + row)) * 2048 + h * HEAD_DIM + dseg;
  for (int dv = 0; dv < 8; ++dv) {
    float acc[8] = {};
    for (int i = 0; i < nc; ++i) {
      bf16x8 o = *(const bf16x8*)&Opart[((size_t)(cid0 + i) * 64 + row) * HEAD_DIM + dseg + dv * 8];
      #pragma unroll
      for (int e = 0; e < 8; ++e) acc[e] += wgt[i] * (float)o[e];
    }
    bf16x8 ov;
    #pragma unroll
    for (int e = 0; e < 8; ++e) ov[e] = (bf16)(acc[e] * inv);
    *(bf16x8*)&dst[dv * 8] = ov;
  }
}

// ---------------- launch ----------------
extern "C" void kernel_launch(void* const* d_in, const int* in_sizes, int n_in,
                              void* d_out, int out_size, void* d_ws, size_t ws_size,
                              hipStream_t stream) {
  const float* hs = (const float*)d_in[0];
  const float* Wq = (const float*)d_in[3];
  const float* Wk = (const float*)d_in[4];
  const float* Wv = (const float*)d_in[5];
  const float* Wo = (const float*)d_in[6];
  float* out = (float*)d_out;

  char* ws = (char*)d_ws;
  bf16* hsb  = (bf16*)(ws);                    // 4096x5120        (41,943,040 B)
  bf16* wqkv = (bf16*)(ws + 41943040);         // 4096x5120        (41,943,040 B)
  bf16* qkv  = (bf16*)(ws + 83886080);         // 4096x4096        (33,554,432 B)
  bf16* qr   = (bf16*)(ws + 117440512);        // 2x8x2048x256     (16,777,216 B)
  bf16* kr   = (bf16*)(ws + 134217728);        // 2x4x2048x256     ( 8,388,608 B)
  bf16* vt   = (bf16*)(ws + 142606336);        // 2x4x256x2048     ( 8,388,608 B)
  bf16* ao   = (bf16*)(ws + 150994944);        // 4096x2048        (16,777,216 B)
  bf16* wob  = (bf16*)(ws + 167772160);        // 2560x2048        (10,485,760 B)
  // flash partials overlay hsb/wqkv (dead after gemm1):
  bf16*  opart = (bf16*)(ws);                  // 1280x64x256 bf16 (41,943,040 B)
  float* ml    = (float*)(ws + 41943040);      // 1280x64x2  f32   (   655,360 B)

  hipFuncSetAttribute((const void*)&gemm_pipe<bf16>,     hipFuncAttributeMaxDynamicSharedMemorySize, 131072);
  hipFuncSetAttribute((const void*)&gemm_pipe128<float>, hipFuncAttributeMaxDynamicSharedMemorySize, 65536);

  // fused casts: 47,185,920 elems / 2048 per block = 23040 blocks
  cast_all<<<23040, 256, 0, stream>>>(hs, Wq, Wk, Wv, Wo, (bf16*)ws, wob);

  // QKV projection: (4096x5120) @ (4096x5120)^T -> 4096x4096, grid 16x16=256 wg
  gemm_pipe<bf16><<<dim3(NQKV / 256, ROWS / 256), 512, 131072, stream>>>(hsb, wqkv, qkv, ROWS, NQKV, IND);

  rope_reorder<<<dim3(ROWS, 12), 128, 0, stream>>>(qkv, qr, kr);
  v_transpose<<<dim3(128, BATCH * NKV), 256, 0, stream>>>(qkv, vt);

  flash_attn<<<dim3(16 * CHUNKS_PER_BH), 256, 0, stream>>>(qr, kr, vt, opart, ml);
  flash_merge<<<dim3(16, 32), 256, 0, stream>>>(opart, ml, ao);

  // output projection: (4096x2048) @ (2560x2048)^T -> 4096x2560 fp32, grid 20x32=640 wg
  gemm_pipe128<float><<<dim3(HID / 128, ROWS / 128), 256, 65536, stream>>>(ao, wob, out, ROWS, HID, 2048);
}

// Round 9
// 354.527 us; speedup vs baseline: 1.7461x; 1.7461x over previous
//
#include <hip/hip_runtime.h>
#include <hip/hip_bf16.h>
#include <cstdint>
#include <cstddef>

typedef __bf16 bf16;
typedef bf16 bf16x4 __attribute__((ext_vector_type(4)));
typedef bf16 bf16x8 __attribute__((ext_vector_type(8)));
typedef float f32x4 __attribute__((ext_vector_type(4)));

#define HEAD_DIM 256
#define NHEADS 8
#define NKV 4
#define BATCH 2
#define SEQ 2048
#define IND 5120
#define HID 2560
#define ROWS (BATCH*SEQ)   // 4096
#define NQKV 4096          // 2048 + 1024 + 1024
#define CHUNKS_PER_BH 40   // 128-q tiles: sum over qt=0..15 of ceil((2qt+2)/8)

// longest-chunk-first dispatch order (28 len-8, then len-6, len-4, len-2)
__constant__ int perm40[40] = {
  3,4,6,8,10,11,12,13,15,16,18,19,21,22,23,24,25,26,28,29,30,32,33,34,36,37,38,39,
  2,9,20,35, 1,7,17,31, 0,5,14,27
};

__device__ __forceinline__ f32x4 mfma16(bf16x8 a, bf16x8 b, f32x4 c) {
  return __builtin_amdgcn_mfma_f32_16x16x32_bf16(a, b, c, 0, 0, 0);
}

// ---------------- fused cast fp32 -> bf16 for all 5 tensors ----------------
__global__ void cast_all(const float* __restrict__ hs, const float* __restrict__ wq,
                         const float* __restrict__ wk, const float* __restrict__ wv,
                         const float* __restrict__ wo,
                         bf16* __restrict__ dst01, bf16* __restrict__ dwo) {
  long i = ((long)blockIdx.x * 256 + threadIdx.x) * 8;
  const float* src; bf16* dst;
  if (i < 20971520L)      { src = hs + i;              dst = dst01 + i; }
  else if (i < 31457280L) { src = wq + (i - 20971520); dst = dst01 + i; }
  else if (i < 36700160L) { src = wk + (i - 31457280); dst = dst01 + i; }
  else if (i < 41943040L) { src = wv + (i - 36700160); dst = dst01 + i; }
  else                    { src = wo + (i - 41943040); dst = dwo + (i - 41943040); }
  float4 a = *(const float4*)(src);
  float4 b = *(const float4*)(src + 4);
  bf16x8 o;
  o[0] = (bf16)a.x; o[1] = (bf16)a.y; o[2] = (bf16)a.z; o[3] = (bf16)a.w;
  o[4] = (bf16)b.x; o[5] = (bf16)b.y; o[6] = (bf16)b.z; o[7] = (bf16)b.w;
  *(bf16x8*)dst = o;
}

// ---------------- pipelined BT GEMM 256x256 ----------------
// BK=32, 512 thr / 8 waves (2Mx4N), 4-slot LDS ring (128 KiB), 3 tiles
// prefetched, counted vmcnt, reads-one-iter-ahead, conflict-free swizzle
// slot = chunk ^ ((row>>1)&3).
template<typename OutT>
__global__ __launch_bounds__(512, 2) void gemm_pipe(const bf16* __restrict__ A,
                                                    const bf16* __restrict__ B,
                                                    OutT* __restrict__ C,
                                                    int M, int N, int K) {
  extern __shared__ bf16 smem[];
  const int tid = threadIdx.x;
  const int lane = tid & 63, w = tid >> 6;
  const int wm = w >> 2, wn = w & 3;
  const int l15 = lane & 15, lg = lane >> 4;
  const int gx = gridDim.x;
  const int nwg = gx * gridDim.y;
  const int id = blockIdx.y * gx + blockIdx.x;
  const int nid = (id & 7) * (nwg >> 3) + (id >> 3);   // bijective: nwg % 8 == 0
  const int m0 = (nid / gx) * 256, n0 = (nid % gx) * 256;
  const int NT = K >> 5;   // even, >= 4

  auto stage = [&](int slot, int kt) {
    bf16* sl = smem + slot * 16384;
    #pragma unroll
    for (int i = 0; i < 2; ++i) {
      int cid = i * 512 + tid;
      int sch = (cid & 3) ^ ((cid >> 3) & 3);
      __builtin_amdgcn_global_load_lds(
        (const __attribute__((address_space(1))) void*)(A + (size_t)(m0 + (cid >> 2)) * K + kt * 32 + sch * 8),
        (__attribute__((address_space(3))) void*)(sl + cid * 8), 16, 0, 0);
    }
    #pragma unroll
    for (int i = 0; i < 2; ++i) {
      int cid = i * 512 + tid;
      int sch = (cid & 3) ^ ((cid >> 3) & 3);
      __builtin_amdgcn_global_load_lds(
        (const __attribute__((address_space(1))) void*)(B + (size_t)(n0 + (cid >> 2)) * K + kt * 32 + sch * 8),
        (__attribute__((address_space(3))) void*)(sl + 8192 + cid * 8), 16, 0, 0);
    }
  };

  const int ach = lg ^ ((l15 >> 1) & 3);
  const int aoff = ((wm * 128 + l15) * 4 + ach) * 8;
  const int boff = 8192 + ((wn * 64 + l15) * 4 + ach) * 8;

  auto read_slot = [&](const bf16* sl, bf16x8 (&a)[8], bf16x8 (&b)[4]) {
    #pragma unroll
    for (int mi = 0; mi < 8; ++mi) a[mi] = *(const bf16x8*)&sl[aoff + mi * 512];
    #pragma unroll
    for (int ni = 0; ni < 4; ++ni) b[ni] = *(const bf16x8*)&sl[boff + ni * 512];
  };

  f32x4 acc[8][4] = {};
  auto domfma = [&](bf16x8 (&a)[8], bf16x8 (&b)[4]) {
    __builtin_amdgcn_s_setprio(1);
    #pragma unroll
    for (int ni = 0; ni < 4; ++ni)
      #pragma unroll
      for (int mi = 0; mi < 8; ++mi)
        acc[mi][ni] = mfma16(a[mi], b[ni], acc[mi][ni]);
    __builtin_amdgcn_s_setprio(0);
  };

  bf16x8 aE[8], bE[4], aO[8], bO[4];
  stage(0, 0); stage(1, 1); stage(2, 2);
  asm volatile("s_waitcnt vmcnt(8)" ::: "memory");
  __builtin_amdgcn_s_barrier();
  __builtin_amdgcn_sched_barrier(0);
  read_slot(smem, aE, bE);

  int t = 0;
  for (; t < NT - 2; t += 2) {
    asm volatile("s_waitcnt vmcnt(4)" ::: "memory");
    __builtin_amdgcn_s_barrier();
    __builtin_amdgcn_sched_barrier(0);
    read_slot(smem + ((t + 1) & 3) * 16384, aO, bO);
    { int kt = t + 3; if (kt > NT - 1) kt = NT - 1; stage((t + 3) & 3, kt); }
    domfma(aE, bE);
    asm volatile("s_waitcnt vmcnt(4)" ::: "memory");
    __builtin_amdgcn_s_barrier();
    __builtin_amdgcn_sched_barrier(0);
    read_slot(smem + ((t + 2) & 3) * 16384, aE, bE);
    { int kt = t + 4; if (kt > NT - 1) kt = NT - 1; stage((t + 4) & 3, kt); }
    domfma(aO, bO);
  }
  asm volatile("s_waitcnt vmcnt(4)" ::: "memory");
  __builtin_amdgcn_s_barrier();
  __builtin_amdgcn_sched_barrier(0);
  read_slot(smem + ((NT - 1) & 3) * 16384, aO, bO);
  domfma(aE, bE);
  domfma(aO, bO);

  #pragma unroll
  for (int mi = 0; mi < 8; ++mi)
    #pragma unroll
    for (int ni = 0; ni < 4; ++ni) {
      int row = m0 + wm * 128 + mi * 16 + lg * 4;
      int col = n0 + wn * 64 + ni * 16 + l15;
      #pragma unroll
      for (int r = 0; r < 4; ++r)
        C[(size_t)(row + r) * N + col] = (OutT)acc[mi][ni][r];
    }
}

// ---------------- RoPE + reorder into Q (B,H,S,D) and K (B,KV,S,D) ----------------
__global__ void rope_reorder(const bf16* __restrict__ QKV,
                             bf16* __restrict__ Qr, bf16* __restrict__ Kr) {
  const int row = blockIdx.x;   // b*SEQ + s
  const int slot = blockIdx.y;  // 0..7 q heads, 8..11 k heads
  const int d = threadIdx.x;    // 0..127
  const int b = row >> 11, s = row & 2047;
  const bool isq = slot < 8;
  const int col0 = isq ? slot * HEAD_DIM : 2048 + (slot - 8) * HEAD_DIM;
  float x1 = (float)QKV[(size_t)row * NQKV + col0 + d];
  float x2 = (float)QKV[(size_t)row * NQKV + col0 + d + 128];
  float invf = exp2f((float)d * (-13.287712379549449f / 128.0f)); // 10000^(-d/128)
  float fr = (float)s * invf;
  float sn, cs;
  sincosf(fr, &sn, &cs);
  bf16* dst = isq ? (Qr + ((size_t)(b * NHEADS + slot) * SEQ + s) * HEAD_DIM)
                  : (Kr + ((size_t)(b * NKV + (slot - 8)) * SEQ + s) * HEAD_DIM);
  dst[d]       = (bf16)(x1 * cs - x2 * sn);
  dst[d + 128] = (bf16)(x2 * cs + x1 * sn);
}

// ---------------- V transpose: VT[bkv][d][s] ----------------
__global__ void v_transpose(const bf16* __restrict__ QKV, bf16* __restrict__ VT) {
  __shared__ bf16 tile[64][66];
  const int bkv = blockIdx.y;
  const int b = bkv >> 2, kv = bkv & 3;
  const int st = blockIdx.x & 31, dt = blockIdx.x >> 5;
  const int s0 = st * 64, d0 = dt * 64;
  const int tj = threadIdx.x & 63, ti = threadIdx.x >> 6;
  for (int i = ti; i < 64; i += 4)
    tile[i][tj] = QKV[(size_t)(b * SEQ + s0 + i) * NQKV + 3072 + kv * HEAD_DIM + d0 + tj];
  __syncthreads();
  for (int i = ti; i < 64; i += 4)
    VT[((size_t)bkv * HEAD_DIM + d0 + i) * SEQ + s0 + tj] = tile[tj][i];
}

// ---------------- flash attention v3: 8 waves, QBLK=128, double-buffered K/V ----
// grid = 640 blocks (longest-chunk-first via perm40), 512 thr. Per block:
// q-tile of 128 rows (16/wave), KV chunk of <=8 kvb (64 each). K/V
// double-buffered in dynamic LDS (2x(32K+32K) + pbuf 20K = 148 KiB, 1 blk/CU).
// stage(t+1) issued before compute(t); counted vmcnt(8); raw barriers.
__global__ __launch_bounds__(512, 2) void flash_attn(const bf16* __restrict__ Q,
                                                     const bf16* __restrict__ Kp,
                                                     const bf16* __restrict__ VT,
                                                     bf16* __restrict__ Opart,
                                                     float* __restrict__ ML) {
  extern __shared__ bf16 fsm[];  // K0[16384] K1[16384] V0[16384] V1[16384] pbuf[10240]
  const int tid = threadIdx.x, lane = tid & 63, w = tid >> 6;
  const int l15 = lane & 15, lg = lane >> 4;

  // longest-first dispatch: slot picks chunk shape, bh interleaved fastest
  const int bh = blockIdx.x & 15;
  const int c  = perm40[blockIdx.x >> 4];
  const int cidO = bh * CHUNKS_PER_BH + c;   // original chunk id (Opart/ML layout)
  int qt, ki;
  if (c < 4)       { qt = c;                  ki = 0; }
  else if (c < 12) { qt = 4  + ((c - 4) >> 1);  ki = (c - 4)  & 1; }
  else if (c < 24) { qt = 8  + (c - 12) / 3;    ki = (c - 12) % 3; }
  else             { qt = 12 + ((c - 24) >> 2); ki = (c - 24) & 3; }
  const int kb0 = ki * 8;
  const int kb1 = min(kb0 + 8, 2 * qt + 2);

  const int b = bh >> 3, h = bh & 7, kvh = h >> 1;
  const int bkv = b * NKV + kvh;
  const int q0 = qt * 128 + w * 16;

  const bf16* Qb = Q + ((size_t)bh * SEQ + q0) * HEAD_DIM;
  bf16x8 qf[8];
  #pragma unroll
  for (int dc = 0; dc < 8; ++dc)
    qf[dc] = *(const bf16x8*)&Qb[l15 * HEAD_DIM + dc * 32 + lg * 8];

  f32x4 oacc[16] = {};
  float m = -1e30f, l = 0.f;

  const bf16* Ksrc = Kp + (size_t)bkv * SEQ * HEAD_DIM;
  const bf16* Vsrc = VT + (size_t)bkv * HEAD_DIM * SEQ;
  bf16* pb = fsm + 65536 + w * 16 * 80;   // [16][80] per wave

  auto stage = [&](int kb, int bi) {
    const int kbase = kb * 64;
    bf16* kd = fsm + bi * 16384;
    bf16* vd = fsm + 32768 + bi * 16384;
    #pragma unroll
    for (int i = 0; i < 4; ++i) {        // K: 64 rows x 256 d, swz on 16B chunks
      int id = i * 512 + tid;
      int row = id >> 5, ch = id & 31;
      int sc = ch ^ (row & 7);
      __builtin_amdgcn_global_load_lds(
          (const __attribute__((address_space(1))) void*)(Ksrc + (size_t)(kbase + row) * HEAD_DIM + sc * 8),
          (__attribute__((address_space(3))) void*)(kd + id * 8), 16, 0, 0);
    }
    #pragma unroll
    for (int i = 0; i < 4; ++i) {        // V^T: 256 d-rows x 64 s
      int id = i * 512 + tid;
      int row = id >> 3, ch = id & 7;
      int sc = ch ^ (row & 7);
      __builtin_amdgcn_global_load_lds(
          (const __attribute__((address_space(1))) void*)(Vsrc + (size_t)row * SEQ + kbase + sc * 8),
          (__attribute__((address_space(3))) void*)(vd + id * 8), 16, 0, 0);
    }
  };

  stage(kb0, 0);   // 8 loads in flight

  for (int kb = kb0; kb < kb1; ++kb) {
    const int bufc = (kb - kb0) & 1;
    const int kbase = kb * 64;
    if (kb + 1 < kb1) {
      stage(kb + 1, bufc ^ 1);
      asm volatile("s_waitcnt vmcnt(8)" ::: "memory");   // kb's loads landed
    } else {
      asm volatile("s_waitcnt vmcnt(0)" ::: "memory");
    }
    asm volatile("s_barrier" ::: "memory");
    const bf16* Ksc = fsm + bufc * 16384;
    const bf16* Vsc = fsm + 32768 + bufc * 16384;

    // ---- S^T = K Q^T ----
    f32x4 sacc[4] = {};
    __builtin_amdgcn_s_setprio(1);
    #pragma unroll
    for (int j = 0; j < 4; ++j) {
      const bf16* kl = &Ksc[(j * 16 + l15) * HEAD_DIM];
      #pragma unroll
      for (int dc = 0; dc < 8; ++dc) {
        int ch = (dc * 4 + lg) ^ (l15 & 7);
        bf16x8 kf = *(const bf16x8*)&kl[ch * 8];
        sacc[j] = mfma16(kf, qf[dc], sacc[j]);
      }
    }
    __builtin_amdgcn_s_setprio(0);

    // ---- mask + scale ----
    float px[4][4];
    const bool need_mask = (kbase + 63 > q0);
    #pragma unroll
    for (int j = 0; j < 4; ++j)
      #pragma unroll
      for (int r = 0; r < 4; ++r) {
        float v = sacc[j][r] * 0.0625f;   // 1/sqrt(256)
        if (need_mask) {
          int kcol = kbase + j * 16 + lg * 4 + r;
          v = (kcol <= q0 + l15) ? v : -1e30f;
        }
        px[j][r] = v;
      }

    // ---- online softmax (lane holds full 16-val row; 2 shfls) ----
    float mx = px[0][0];
    #pragma unroll
    for (int j = 0; j < 4; ++j)
      #pragma unroll
      for (int r = 0; r < 4; ++r) mx = fmaxf(mx, px[j][r]);
    mx = fmaxf(mx, __shfl_xor(mx, 16));
    mx = fmaxf(mx, __shfl_xor(mx, 32));
    float mnew = fmaxf(m, mx);
    float alpha = __expf(m - mnew);
    m = mnew;
    float s = 0.f;
    #pragma unroll
    for (int j = 0; j < 4; ++j) {
      bf16x4 pk;
      #pragma unroll
      for (int r = 0; r < 4; ++r) {
        float e = __expf(px[j][r] - mnew);
        s += e;
        pk[r] = (bf16)e;
      }
      *(bf16x4*)&pb[l15 * 80 + j * 16 + lg * 4] = pk;
    }
    s += __shfl_xor(s, 16);
    s += __shfl_xor(s, 32);
    l = l * alpha + s;

    float ar[4];
    #pragma unroll
    for (int r = 0; r < 4; ++r) ar[r] = __shfl(alpha, lg * 4 + r);
    #pragma unroll
    for (int ni = 0; ni < 16; ++ni)
      #pragma unroll
      for (int r = 0; r < 4; ++r) oacc[ni][r] *= ar[r];

    // ---- O += P V ----
    bf16x8 pa0 = *(const bf16x8*)&pb[l15 * 80 + lg * 8];
    bf16x8 pa1 = *(const bf16x8*)&pb[l15 * 80 + 32 + lg * 8];
    __builtin_amdgcn_s_setprio(1);
    #pragma unroll
    for (int ni = 0; ni < 16; ++ni) {
      const bf16* vb = &Vsc[(ni * 16 + l15) * 64];
      int c0 = lg ^ (l15 & 7);
      int c1 = (4 + lg) ^ (l15 & 7);
      bf16x8 v0 = *(const bf16x8*)&vb[c0 * 8];
      bf16x8 v1 = *(const bf16x8*)&vb[c1 * 8];
      oacc[ni] = mfma16(pa0, v0, oacc[ni]);
      oacc[ni] = mfma16(pa1, v1, oacc[ni]);
    }
    __builtin_amdgcn_s_setprio(0);
    asm volatile("s_barrier" ::: "memory");   // frees bufc for stage at kb+2
  }

  bf16* Ob = Opart + ((size_t)cidO * 128 + w * 16) * HEAD_DIM;
  #pragma unroll
  for (int ni = 0; ni < 16; ++ni)
    #pragma unroll
    for (int r = 0; r < 4; ++r)
      Ob[(size_t)(lg * 4 + r) * HEAD_DIM + ni * 16 + l15] = (bf16)oacc[ni][r];
  if (lg == 0) {
    ML[((size_t)cidO * 128 + w * 16 + l15) * 2]     = m;
    ML[((size_t)cidO * 128 + w * 16 + l15) * 2 + 1] = l;
  }
}

// ---------------- merge partials -> ao (b, s, h*256+d) bf16 ----------------
__global__ __launch_bounds__(256) void flash_merge(const bf16* __restrict__ Opart,
                                                   const float* __restrict__ ML,
                                                   bf16* __restrict__ AO) {
  const int bh = blockIdx.x, qt = blockIdx.y;   // 16 x 16
  const int b = bh >> 3, h = bh & 7;
  const int g = qt >> 2;
  const int nc = g + 1;
  int cbase;
  if (g == 0)      cbase = qt;
  else if (g == 1) cbase = 4  + 2 * (qt - 4);
  else if (g == 2) cbase = 12 + 3 * (qt - 8);
  else             cbase = 24 + 4 * (qt - 12);
  const int cid0 = bh * CHUNKS_PER_BH + cbase;

  const int tid = threadIdx.x;
  const int row = tid >> 1, dh = (tid & 1) * 128;

  float mi[4], li[4];
  float M = -1e30f;
  for (int i = 0; i < nc; ++i) {
    mi[i] = ML[((size_t)(cid0 + i) * 128 + row) * 2];
    li[i] = ML[((size_t)(cid0 + i) * 128 + row) * 2 + 1];
    M = fmaxf(M, mi[i]);
  }
  float wgt[4], L = 0.f;
  for (int i = 0; i < nc; ++i) {
    wgt[i] = __expf(mi[i] - M);
    L += li[i] * wgt[i];
  }
  const float inv = 1.0f / L;

  bf16* dst = AO + ((size_t)(b * SEQ + qt * 128 + row)) * 2048 + h * HEAD_DIM + dh;
  for (int dv = 0; dv < 16; ++dv) {
    float acc[8] = {};
    for (int i = 0; i < nc; ++i) {
      bf16x8 o = *(const bf16x8*)&Opart[((size_t)(cid0 + i) * 128 + row) * HEAD_DIM + dh + dv * 8];
      #pragma unroll
      for (int e = 0; e < 8; ++e) acc[e] += wgt[i] * (float)o[e];
    }
    bf16x8 ov;
    #pragma unroll
    for (int e = 0; e < 8; ++e) ov[e] = (bf16)(acc[e] * inv);
    *(bf16x8*)&dst[dv * 8] = ov;
  }
}

// ---------------- launch ----------------
extern "C" void kernel_launch(void* const* d_in, const int* in_sizes, int n_in,
                              void* d_out, int out_size, void* d_ws, size_t ws_size,
                              hipStream_t stream) {
  const float* hs = (const float*)d_in[0];
  const float* Wq = (const float*)d_in[3];
  const float* Wk = (const float*)d_in[4];
  const float* Wv = (const float*)d_in[5];
  const float* Wo = (const float*)d_in[6];
  float* out = (float*)d_out;

  char* ws = (char*)d_ws;
  bf16* hsb  = (bf16*)(ws);                    // 4096x5120        (41,943,040 B)
  bf16* wqkv = (bf16*)(ws + 41943040);         // 4096x5120        (41,943,040 B)
  bf16* qkv  = (bf16*)(ws + 83886080);         // 4096x4096        (33,554,432 B)
  bf16* qr   = (bf16*)(ws + 117440512);        // 2x8x2048x256     (16,777,216 B)
  bf16* kr   = (bf16*)(ws + 134217728);        // 2x4x2048x256     ( 8,388,608 B)
  bf16* vt   = (bf16*)(ws + 142606336);        // 2x4x256x2048     ( 8,388,608 B)
  bf16* ao   = (bf16*)(ws + 150994944);        // 4096x2048        (16,777,216 B)
  bf16* wob  = (bf16*)(ws + 167772160);        // 2560x2048        (10,485,760 B)
  // flash partials overlay hsb/wqkv (dead after gemm1):
  bf16*  opart = (bf16*)(ws);                  // 640x128x256 bf16 (41,943,040 B)
  float* ml    = (float*)(ws + 41943040);      // 640x128x2  f32   (   655,360 B)

  hipFuncSetAttribute((const void*)&gemm_pipe<bf16>,  hipFuncAttributeMaxDynamicSharedMemorySize, 131072);
  hipFuncSetAttribute((const void*)&gemm_pipe<float>, hipFuncAttributeMaxDynamicSharedMemorySize, 131072);
  hipFuncSetAttribute((const void*)&flash_attn,       hipFuncAttributeMaxDynamicSharedMemorySize, 151552);

  // fused casts: 47,185,920 elems / 2048 per block = 23040 blocks
  cast_all<<<23040, 256, 0, stream>>>(hs, Wq, Wk, Wv, Wo, (bf16*)ws, wob);

  // QKV projection: (4096x5120) @ (4096x5120)^T -> 4096x4096, grid 16x16=256 wg
  gemm_pipe<bf16><<<dim3(NQKV / 256, ROWS / 256), 512, 131072, stream>>>(hsb, wqkv, qkv, ROWS, NQKV, IND);

  rope_reorder<<<dim3(ROWS, 12), 128, 0, stream>>>(qkv, qr, kr);
  v_transpose<<<dim3(128, BATCH * NKV), 256, 0, stream>>>(qkv, vt);

  flash_attn<<<dim3(16 * CHUNKS_PER_BH), 512, 151552, stream>>>(qr, kr, vt, opart, ml);
  flash_merge<<<dim3(16, 16), 256, 0, stream>>>(opart, ml, ao);

  // output projection: (4096x2048) @ (2560x2048)^T -> 4096x2560 fp32, grid 10x16=160 wg
  gemm_pipe<float><<<dim3(HID / 256, ROWS / 256), 512, 131072, stream>>>(ao, wob, out, ROWS, HID, 2048);
}